// Round 7
// baseline (285.020 us; speedup 1.0000x reference)
//
#include <hip/hip_runtime.h>
#include <hip/hip_bf16.h>
#include <math.h>

typedef __attribute__((ext_vector_type(8))) short short8;
typedef __attribute__((ext_vector_type(4))) float f32x4;

#define NJ 24

// ---- ws image: per-fragment 1KB blocks (64 lanes x 16B), lane-major ----
// GEMM1: per joint 15 blocks (blk=nt*3+s)  lane(rm,g): W1T[n=nt*16+rm][k'=s*32+g*8..+7]
// GEMM2: per joint 12 blocks (blk=nt*3+s)  W2T[n][k]
// Wp   : 36 blocks (blk=nt*9+s)            WpT[n][k']  k' in [pose216|rel72] order
#define F1_J   7680
#define F2_OFF (NJ*F1_J)
#define F2_J   6144
#define FP_OFF (F2_OFF + NJ*F2_J)
#define IMG_SHORTS (FP_OFF + 36*512)        // 350208 shorts = 700416 B

#define MFMA(A,B,C) __builtin_amdgcn_mfma_f32_16x16x32_bf16((A),(B),(C),0,0,0)

// flat level order: [0 | 1,2,3 | 4,5,6 | 7,8,9 | 10..14 | 15,16,17 | 18,19 | 20,21 | 22,23]
__constant__ int LVLJ[24] = {0, 1,2,3, 4,5,6, 7,8,9, 10,11,12,13,14, 15,16,17, 18,19, 20,21, 22,23};
__constant__ int LVLP[24] = {-1,0,0,0, 1,2,3, 4,5,6, 7,8,9,9,9,     12,13,14, 16,17, 18,19, 20,21};

__device__ __forceinline__ short f2bf(float f) {      // prep only
  union { float f; unsigned u; } v; v.f = f;
  unsigned r = v.u + 0x7FFFu + ((v.u >> 16) & 1u);    // RNE
  return (short)(r >> 16);
}
__device__ __forceinline__ short sbf(float f) {
  __hip_bfloat16 h = __float2bfloat16(f);
  return *reinterpret_cast<short*>(&h);
}
__device__ __forceinline__ short8 pk8(f32x4 lo, f32x4 hi) {
  union { short8 s; unsigned u[4]; } r;
  asm("v_cvt_pk_bf16_f32 %0, %1, %2" : "=v"(r.u[0]) : "v"(lo[0]), "v"(lo[1]));
  asm("v_cvt_pk_bf16_f32 %0, %1, %2" : "=v"(r.u[1]) : "v"(lo[2]), "v"(lo[3]));
  asm("v_cvt_pk_bf16_f32 %0, %1, %2" : "=v"(r.u[2]) : "v"(hi[0]), "v"(hi[1]));
  asm("v_cvt_pk_bf16_f32 %0, %1, %2" : "=v"(r.u[3]) : "v"(hi[2]), "v"(hi[3]));
  return r.s;
}
// async global->LDS 16B/lane; dst chunk base wave-uniform by construction
__device__ __forceinline__ void stage256(const short* __restrict__ src,
                                         short* dst, int n16, int tid, int lane) {
#pragma unroll 1
  for (int t = tid; t < n16; t += 256)
    __builtin_amdgcn_global_load_lds(
        (const __attribute__((address_space(1))) void*)(src + (size_t)t*8),
        (__attribute__((address_space(3))) void*)(dst + (t - lane)*8), 16, 0, 0);
}

__global__ __launch_bounds__(256) void prep_kernel(
    const float* __restrict__ W1, const float* __restrict__ W2,
    const float* __restrict__ Wp, short* __restrict__ img) {
  int t = blockIdx.x * 256 + threadIdx.x;
  if (t >= IMG_SHORTS) return;
  float v = 0.f;
  if (t < F2_OFF) {
    int i = t / F1_J, r = t % F1_J;
    int blk = r >> 9, q = r & 511;
    int ln = q >> 3, e = q & 7;
    int nt = blk / 3, s = blk - nt*3;
    int n  = nt*16 + (ln & 15);
    int kp = s*32 + (ln >> 4)*8 + e;                 // x: [0..12]bt [13..15]0 [16..79]feat [80..95]0
    if (n < 77) {
      if (kp < 13)                  v = W1[i*5929 + kp*77 + n];
      else if (kp >= 16 && kp < 80) v = W1[i*5929 + (kp-3)*77 + n];
    }
  } else if (t < FP_OFF) {
    int u = t - F2_OFF;
    int i = u / F2_J, r = u % F2_J;
    int blk = r >> 9, q = r & 511;
    int ln = q >> 3, e = q & 7;
    int nt = blk / 3, s = blk - nt*3;
    int n  = nt*16 + (ln & 15);
    int k  = s*32 + (ln >> 4)*8 + e;
    if (k < 77) v = W2[i*4928 + k*64 + n];
  } else {
    // WpT rows permuted to the A-side's [pose 216 | rel 72] direct-load order
    int u = t - FP_OFF;
    int blk = u >> 9, q = u & 511;
    int ln = q >> 3, e = q & 7;
    int nt = blk / 9, s = blk - nt*9;
    int n  = nt*16 + (ln & 15);
    int kp = s*32 + (ln >> 4)*8 + e;                 // k' < 288
    int j, w;
    if (kp < 216) { j = kp / 9;       w = kp % 9; }
    else          { j = (kp-216) / 3; w = 9 + (kp-216) % 3; }
    v = Wp[(j*12 + w)*64 + n];
  }
  img[t] = f2bf(v);
}

// K0: root prior (K=288) + joint 0, no barriers, 4 waves x 16 rows.
__global__ __launch_bounds__(256, 2) void k0_kernel(
    const float* __restrict__ pose, const float* __restrict__ rel,
    const float* __restrict__ bp,  const float* __restrict__ b1w,
    const float* __restrict__ b2w, const short* __restrict__ img,
    float* __restrict__ out) {
  __shared__ __align__(16) short lds[4*2560];        // per wave: feat[16][72] + h[16][88]
  const int tid = threadIdx.x, lane = tid & 63, wv = tid >> 6;
  short* featL = lds + wv*2560;
  short* hw    = lds + wv*2560 + 1152;
  const int cl = lane & 15, g = lane >> 4;
  const int rw0 = blockIdx.x*64 + wv*16;
  const short8 zz = {0,0,0,0,0,0,0,0};

  const float* pr = pose + (size_t)(rw0 + cl)*216;
  const float* rr = rel  + (size_t)(rw0 + cl)*72;

  // ---- prior: bonefeat(16x288) @ WpT + bp -> featL ----
  f32x4 racc[4] = {{0,0,0,0},{0,0,0,0},{0,0,0,0},{0,0,0,0}};
  {
    const short8* fpg = (const short8*)(img + FP_OFF) + lane;
    short8 av[9];
#pragma unroll
    for (int s = 0; s < 9; ++s) {
      int k0 = s*32 + g*8;
      const float* src = (k0 < 216) ? (pr + k0) : (rr + (k0 - 216));
      av[s] = pk8(*(const f32x4*)src, *(const f32x4*)(src + 4));
    }
#pragma unroll
    for (int nt = 0; nt < 4; ++nt) {
      short8 fwp[9];
#pragma unroll
      for (int s = 0; s < 9; ++s) fwp[s] = fpg[(nt*9 + s)*64];
#pragma unroll
      for (int s = 0; s < 9; ++s) racc[nt] = MFMA(av[s], fwp[s], racc[nt]);
    }
  }
  // joint-0 weights issued now (flight across epilogue)
  short8 fw1[15], fw2[12];
  {
    const short8* f1g = (const short8*)img + lane;
    const short8* f2g = (const short8*)(img + F2_OFF) + lane;
#pragma unroll
    for (int b = 0; b < 15; ++b) fw1[b] = f1g[b*64];
#pragma unroll
    for (int b = 0; b < 12; ++b) fw2[b] = f2g[b*64];
  }
#pragma unroll
  for (int nt = 0; nt < 4; ++nt) {
    int n = nt*16 + cl;
    float bias = bp[n];
#pragma unroll
    for (int r4 = 0; r4 < 4; ++r4)
      featL[(g*4 + r4)*72 + n] = sbf(racc[nt][r4] + bias);
  }

  // ---- joint 0 ----
  const short* fb = featL + cl*72;
  short8 a0, a1, a2;
  if (g == 0) {           // bt cols 0..7 = pose[0..7] (joint 0: 16B-aligned)
    a0 = pk8(*(const f32x4*)pr, *(const f32x4*)(pr + 4));
  } else if (g == 1) {    // [pose8, rel0..2, |rel|, 0,0,0]
    f32x4 q = *(const f32x4*)rr;
    float nv = sqrtf(q[0]*q[0] + q[1]*q[1] + q[2]*q[2]);
    a0[0] = sbf(pr[8]); a0[1] = sbf(q[0]); a0[2] = sbf(q[1]); a0[3] = sbf(q[2]);
    a0[4] = sbf(nv);    a0[5] = 0; a0[6] = 0; a0[7] = 0;
  } else {
    a0 = *(const short8*)(fb + (g-2)*8);
  }
  a1 = *(const short8*)(fb + 16 + g*8);
  a2 = (g < 2) ? *(const short8*)(fb + 48 + g*8) : zz;

  f32x4 acc1[5] = {{0,0,0,0},{0,0,0,0},{0,0,0,0},{0,0,0,0},{0,0,0,0}};
#pragma unroll
  for (int nt = 0; nt < 5; ++nt) {
    acc1[nt] = MFMA(a0, fw1[nt*3+0], acc1[nt]);
    acc1[nt] = MFMA(a1, fw1[nt*3+1], acc1[nt]);
    acc1[nt] = MFMA(a2, fw1[nt*3+2], acc1[nt]);
  }
#pragma unroll
  for (int nt = 0; nt < 5; ++nt) {
    int n = nt*16 + cl;
    float bias = (n < 77) ? b1w[n] : 0.f;
#pragma unroll
    for (int r4 = 0; r4 < 4; ++r4)
      hw[(g*4 + r4)*88 + n] = sbf(fmaxf(acc1[nt][r4] + bias, 0.f));
  }
  short8 h0 = *(const short8*)(hw + cl*88 + g*8);
  short8 h1 = *(const short8*)(hw + cl*88 + 32 + g*8);
  short8 h2 = (g < 2) ? *(const short8*)(hw + cl*88 + 64 + g*8) : zz;
  f32x4 acc2[4] = {{0,0,0,0},{0,0,0,0},{0,0,0,0},{0,0,0,0}};
#pragma unroll
  for (int nt = 0; nt < 4; ++nt) {
    acc2[nt] = MFMA(h0, fw2[nt*3+0], acc2[nt]);
    acc2[nt] = MFMA(h1, fw2[nt*3+1], acc2[nt]);
    acc2[nt] = MFMA(h2, fw2[nt*3+2], acc2[nt]);
  }
  float* outb = out + (size_t)(rw0 + g*4)*1536;       // joint 0 cols
#pragma unroll
  for (int nt = 0; nt < 4; ++nt) {
    int n = nt*16 + cl;
    float bias = b2w[n];
#pragma unroll
    for (int r4 = 0; r4 < 4; ++r4)
      outb[(size_t)r4*1536 + n] = fmaxf(acc2[nt][r4] + bias, 0.f);
  }
}

// KL: one (64-row, joint) tile per WG. Weights LDS-shared (one barrier),
// parent feat read f32-direct from out, h via wave-private LDS.
__global__ __launch_bounds__(256, 4) void kl_kernel(
    const float* __restrict__ pose, const float* __restrict__ rel,
    const float* __restrict__ b1w,  const float* __restrict__ b2w,
    const short* __restrict__ img,  float* __restrict__ out, int loff) {
  __shared__ __align__(16) short wgt[13824];          // W1T 7680 | W2T 6144
  __shared__ __align__(16) short hAll[4*1408];        // per-wave h[16][88]
  const int tid = threadIdx.x, lane = tid & 63, wv = tid >> 6;
  const int cl = lane & 15, g = lane >> 4;
  const int rw0 = blockIdx.x*64 + wv*16;
  const int bj = loff + (int)blockIdx.y;
  const int j  = LVLJ[bj], pj = LVLP[bj];
  short* hw = hAll + wv*1408;
  const short8 zz = {0,0,0,0,0,0,0,0};

  // 1) issue parent-feat (f32) + bt loads
  const float* fbase = out + (size_t)(rw0 + cl)*1536 + (size_t)pj*64;
  f32x4 a1lo = *(const f32x4*)(fbase + 16 + g*8);
  f32x4 a1hi = *(const f32x4*)(fbase + 20 + g*8);
  const int s0 = (g < 2) ? 0 : (g-2)*8;
  f32x4 a0lo = *(const f32x4*)(fbase + s0);
  f32x4 a0hi = *(const f32x4*)(fbase + s0 + 4);
  const int s2 = (g < 2) ? (48 + g*8) : 16;
  f32x4 a2lo = *(const f32x4*)(fbase + s2);
  f32x4 a2hi = *(const f32x4*)(fbase + s2 + 4);
  const float* pr = pose + (size_t)(rw0 + cl)*216 + (size_t)j*9;
  const float* rr = rel  + (size_t)(rw0 + cl)*72  + (size_t)j*3;
  float p0=0,p1=0,p2=0,p3=0,p4=0,p5=0,p6=0,p7=0, p8=0, q0=0,q1=0,q2=0;
  if (g == 0) { p0=pr[0]; p1=pr[1]; p2=pr[2]; p3=pr[3];
                p4=pr[4]; p5=pr[5]; p6=pr[6]; p7=pr[7]; }
  else if (g == 1) { p8=pr[8]; q0=rr[0]; q1=rr[1]; q2=rr[2]; }

  // 2) async weight staging (stays in flight while we convert)
  stage256(img + (size_t)j*F1_J, wgt, 960, tid, lane);
  stage256(img + F2_OFF + (size_t)j*F2_J, wgt + 7680, 768, tid, lane);

  // 3) build A fragments
  short8 a0, a1 = pk8(a1lo, a1hi), a2;
  if (g == 0) {
    a0[0]=sbf(p0); a0[1]=sbf(p1); a0[2]=sbf(p2); a0[3]=sbf(p3);
    a0[4]=sbf(p4); a0[5]=sbf(p5); a0[6]=sbf(p6); a0[7]=sbf(p7);
  } else if (g == 1) {
    float nv = sqrtf(q0*q0 + q1*q1 + q2*q2);
    a0[0]=sbf(p8); a0[1]=sbf(q0); a0[2]=sbf(q1); a0[3]=sbf(q2);
    a0[4]=sbf(nv); a0[5]=0; a0[6]=0; a0[7]=0;
  } else {
    a0 = pk8(a0lo, a0hi);
  }
  a2 = (g < 2) ? pk8(a2lo, a2hi) : zz;

  __syncthreads();                                    // weights ready (only barrier)

  // 4) GEMM1 from LDS weights
  const short8* f1 = (const short8*)wgt + lane;
  f32x4 acc1[5] = {{0,0,0,0},{0,0,0,0},{0,0,0,0},{0,0,0,0},{0,0,0,0}};
#pragma unroll
  for (int nt = 0; nt < 5; ++nt) {
    acc1[nt] = MFMA(a0, f1[(nt*3+0)*64], acc1[nt]);
    acc1[nt] = MFMA(a1, f1[(nt*3+1)*64], acc1[nt]);
    acc1[nt] = MFMA(a2, f1[(nt*3+2)*64], acc1[nt]);
  }
  const float* b1i = b1w + j*77;
#pragma unroll
  for (int nt = 0; nt < 5; ++nt) {
    int n = nt*16 + cl;
    float bias = (n < 77) ? b1i[n] : 0.f;
#pragma unroll
    for (int r4 = 0; r4 < 4; ++r4)
      hw[(g*4 + r4)*88 + n] = sbf(fmaxf(acc1[nt][r4] + bias, 0.f));
  }
  short8 h0 = *(const short8*)(hw + cl*88 + g*8);
  short8 h1 = *(const short8*)(hw + cl*88 + 32 + g*8);
  short8 h2 = (g < 2) ? *(const short8*)(hw + cl*88 + 64 + g*8) : zz;
  const short8* f2 = (const short8*)(wgt + 7680) + lane;
  f32x4 acc2[4] = {{0,0,0,0},{0,0,0,0},{0,0,0,0},{0,0,0,0}};
#pragma unroll
  for (int nt = 0; nt < 4; ++nt) {
    acc2[nt] = MFMA(h0, f2[(nt*3+0)*64], acc2[nt]);
    acc2[nt] = MFMA(h1, f2[(nt*3+1)*64], acc2[nt]);
    acc2[nt] = MFMA(h2, f2[(nt*3+2)*64], acc2[nt]);
  }
  const float* b2i = b2w + j*64;
  float* outb = out + (size_t)(rw0 + g*4)*1536 + (size_t)j*64;
#pragma unroll
  for (int nt = 0; nt < 4; ++nt) {
    int n = nt*16 + cl;
    float bias = b2i[n];
#pragma unroll
    for (int r4 = 0; r4 < 4; ++r4)
      outb[(size_t)r4*1536 + n] = fmaxf(acc2[nt][r4] + bias, 0.f);
  }
}

extern "C" void kernel_launch(void* const* d_in, const int* in_sizes, int n_in,
                              void* d_out, int out_size, void* d_ws, size_t ws_size,
                              hipStream_t stream) {
  const float* pose = (const float*)d_in[0];
  const float* rel  = (const float*)d_in[1];
  const float* Wp   = (const float*)d_in[2];
  const float* bp   = (const float*)d_in[3];
  const float* W1   = (const float*)d_in[4];
  const float* b1   = (const float*)d_in[5];
  const float* W2   = (const float*)d_in[6];
  const float* b2   = (const float*)d_in[7];
  float* outp = (float*)d_out;
  short* img  = (short*)d_ws;            // 700,416 B scratch
  const int Bn = in_sizes[0] / 216;
  static const int LOFF[9] = {1,4,7,10,15,18,20,22,24};

  prep_kernel<<<(IMG_SHORTS + 255)/256, 256, 0, stream>>>(W1, W2, Wp, img);
  k0_kernel<<<Bn/64, 256, 0, stream>>>(pose, rel, bp, b1, b2, img, outp);
  for (int l = 0; l < 8; ++l) {
    int cnt = LOFF[l+1] - LOFF[l];
    kl_kernel<<<dim3(Bn/64, cnt), 256, 0, stream>>>(pose, rel, b1, b2, img, outp, LOFF[l]);
  }
}

// Round 8
// 213.004 us; speedup vs baseline: 1.3381x; 1.3381x over previous
//
#include <hip/hip_runtime.h>
#include <hip/hip_bf16.h>
#include <math.h>

typedef __attribute__((ext_vector_type(8))) short short8;
typedef __attribute__((ext_vector_type(4))) float f32x4;

#define NJ 24

// ---- ws image: per-fragment 1KB blocks (64 lanes x 16B), lane-major ----
// GEMM1: per joint 15 blocks (blk=nt*3+s)  lane(rm,g): W1T[n=nt*16+rm][k'=s*32+g*8..+7]
// GEMM2: per joint 12 blocks (blk=nt*3+s)  W2T[n][k]
// Wp   : 36 blocks (blk=nt*9+s)            WpT[n][k']  k' in [pose216|rel72] order
#define F1_J   7680
#define F2_OFF (NJ*F1_J)
#define F2_J   6144
#define FP_OFF (F2_OFF + NJ*F2_J)
#define IMG_SHORTS (FP_OFF + 36*512)        // 350208 shorts = 700416 B

#define MFMA(A,B,C) __builtin_amdgcn_mfma_f32_16x16x32_bf16((A),(B),(C),0,0,0)

// DFS topological order over PARENTS + 3-slot liveness schedule (verified R5/R6)
__constant__ int ORD[24] = {0,1,4,7,10, 2,5,8,11, 3,6,9, 12,15, 13,16,18,20,22, 14,17,19,21,23};
__constant__ int PSL[24] = {2,0,1,1,1,  0,1,1,1,  0,0,0,  0,1,   0,1,1,1,1,    0,0,0,0,0};
__constant__ int SSL[24] = {0,1,1,1,-1, 1,1,1,-1, 0,0,0,  1,-1,  1,1,1,1,-1,   0,0,0,0,-1};

__device__ __forceinline__ short f2bf(float f) {      // prep only
  union { float f; unsigned u; } v; v.f = f;
  unsigned r = v.u + 0x7FFFu + ((v.u >> 16) & 1u);    // RNE
  return (short)(r >> 16);
}
__device__ __forceinline__ short sbf(float f) {
  __hip_bfloat16 h = __float2bfloat16(f);
  return *reinterpret_cast<short*>(&h);
}
__device__ __forceinline__ short8 pk8(f32x4 lo, f32x4 hi) {
  union { short8 s; unsigned u[4]; } r;
  asm("v_cvt_pk_bf16_f32 %0, %1, %2" : "=v"(r.u[0]) : "v"(lo[0]), "v"(lo[1]));
  asm("v_cvt_pk_bf16_f32 %0, %1, %2" : "=v"(r.u[1]) : "v"(lo[2]), "v"(lo[3]));
  asm("v_cvt_pk_bf16_f32 %0, %1, %2" : "=v"(r.u[2]) : "v"(hi[0]), "v"(hi[1]));
  asm("v_cvt_pk_bf16_f32 %0, %1, %2" : "=v"(r.u[3]) : "v"(hi[2]), "v"(hi[3]));
  return r.s;
}

__global__ __launch_bounds__(256) void prep_kernel(
    const float* __restrict__ W1, const float* __restrict__ W2,
    const float* __restrict__ Wp, short* __restrict__ img) {
  int t = blockIdx.x * 256 + threadIdx.x;
  if (t >= IMG_SHORTS) return;
  float v = 0.f;
  if (t < F2_OFF) {
    int i = t / F1_J, r = t % F1_J;
    int blk = r >> 9, q = r & 511;
    int ln = q >> 3, e = q & 7;
    int nt = blk / 3, s = blk - nt*3;
    int n  = nt*16 + (ln & 15);
    int kp = s*32 + (ln >> 4)*8 + e;                 // x: [0..12]bt [13..15]0 [16..79]feat [80..95]0
    if (n < 77) {
      if (kp < 13)                  v = W1[i*5929 + kp*77 + n];
      else if (kp >= 16 && kp < 80) v = W1[i*5929 + (kp-3)*77 + n];
    }
  } else if (t < FP_OFF) {
    int u = t - F2_OFF;
    int i = u / F2_J, r = u % F2_J;
    int blk = r >> 9, q = r & 511;
    int ln = q >> 3, e = q & 7;
    int nt = blk / 3, s = blk - nt*3;
    int n  = nt*16 + (ln & 15);
    int k  = s*32 + (ln >> 4)*8 + e;
    if (k < 77) v = W2[i*4928 + k*64 + n];
  } else {
    // WpT rows permuted to the A-side's [pose 216 | rel 72] direct-load order
    int u = t - FP_OFF;
    int blk = u >> 9, q = u & 511;
    int ln = q >> 3, e = q & 7;
    int nt = blk / 9, s = blk - nt*9;
    int n  = nt*16 + (ln & 15);
    int kp = s*32 + (ln >> 4)*8 + e;                 // k' < 288
    int j, w;
    if (kp < 216) { j = kp / 9;       w = kp % 9; }
    else          { j = (kp-216) / 3; w = 9 + (kp-216) % 3; }
    v = Wp[(j*12 + w)*64 + n];
  }
  img[t] = f2bf(v);
}

// bt for 32-row waves: lane = r*2+q (r=0..31, q=0..1)
// q=0 -> cols 0..7 (pose 0..7), q=1 -> cols 8..15 = [pose8, rel0..2, |rel|, 0,0,0]
struct BT { float p0,p1,p2,p3,p4,p5,p6,p7; };
__device__ __forceinline__ BT bt_load(const float* __restrict__ pose,
                                      const float* __restrict__ rel,
                                      int rw0, int jj, int lane) {
  int r = lane >> 1, q = lane & 1;
  const float* pb = pose + (size_t)(rw0 + r)*216 + (size_t)jj*9;
  const float* rb = rel  + (size_t)(rw0 + r)*72  + (size_t)jj*3;
  BT b;
  if (q == 0) { b.p0=pb[0]; b.p1=pb[1]; b.p2=pb[2]; b.p3=pb[3];
                b.p4=pb[4]; b.p5=pb[5]; b.p6=pb[6]; b.p7=pb[7]; }
  else        { b.p0=pb[8]; b.p1=rb[0]; b.p2=rb[1]; b.p3=rb[2];
                b.p4=0;     b.p5=0;     b.p6=0;     b.p7=0; }
  return b;
}
__device__ __forceinline__ void bt_write(short* btL, BT b, int lane) {
  int r = lane >> 1, q = lane & 1;
  short8 w;
  if (q == 0) {
    w[0]=sbf(b.p0); w[1]=sbf(b.p1); w[2]=sbf(b.p2); w[3]=sbf(b.p3);
    w[4]=sbf(b.p4); w[5]=sbf(b.p5); w[6]=sbf(b.p6); w[7]=sbf(b.p7);
  } else {
    float nv = sqrtf(b.p1*b.p1 + b.p2*b.p2 + b.p3*b.p3);
    w[0]=sbf(b.p0); w[1]=sbf(b.p1); w[2]=sbf(b.p2); w[3]=sbf(b.p3);
    w[4]=sbf(nv);   w[5]=0; w[6]=0; w[7]=0;
  }
  *(short8*)(btL + r*24 + q*8) = w;
}

// 256 threads = 4 waves; each wave owns 32 rows (2 m-tiles) + whole tree. ZERO barriers.
// Per-wave LDS: feat 3x[32][72] | h [32][80] | bt [32][24] = 20,480 B -> 2 WG/CU
__global__ __launch_bounds__(256, 2) void enc_kernel(
    const float* __restrict__ pose, const float* __restrict__ rel,
    const float* __restrict__ bp,  const float* __restrict__ b1,
    const float* __restrict__ b2,  const short* __restrict__ img,
    float* __restrict__ out) {
  __shared__ __align__(16) short lds[4*10240];       // 81,920 B

  const int tid  = threadIdx.x;
  const int lane = tid & 63;
  const int wv   = tid >> 6;
  short* myl   = lds + wv*10240;
  short* featL = myl;                                // 3 slots x [32][72] = 6912
  short* hL    = myl + 6912;                         // [32][80] = 2560
  short* btL   = myl + 9472;                         // [32][24] = 768

  const int cl  = lane & 15;                         // A m-row / C n-col
  const int g   = lane >> 4;                         // k-octet / C row-group
  const int rw0 = blockIdx.x*128 + wv*32;            // wave's first batch row

  const short8 zz = {0,0,0,0,0,0,0,0};

  const short8* f1g = (const short8*)img + lane;
  const short8* f2g = (const short8*)(img + F2_OFF) + lane;
  const short8* fpg = (const short8*)(img + FP_OFF) + lane;

  // bt for joint ORD[0]=0 issued first (written after root)
  BT nb = bt_load(pose, rel, rw0, 0, lane);

  // ---- root: bonefeat(32x288) @ Wp + bp -> feat slot 2 ----
  f32x4 racc[2][4] = {};
  {
    const float* pr0 = pose + (size_t)(rw0 + cl)*216;
    const float* rr0 = rel  + (size_t)(rw0 + cl)*72;
    const float* pr1 = pose + (size_t)(rw0 + 16 + cl)*216;
    const float* rr1 = rel  + (size_t)(rw0 + 16 + cl)*72;
    short8 av0[9], av1[9];
#pragma unroll
    for (int s = 0; s < 9; ++s) {
      int k0 = s*32 + g*8;
      const float* s0 = (k0 < 216) ? (pr0 + k0) : (rr0 + (k0 - 216));
      const float* s1 = (k0 < 216) ? (pr1 + k0) : (rr1 + (k0 - 216));
      av0[s] = pk8(*(const f32x4*)s0, *(const f32x4*)(s0 + 4));
      av1[s] = pk8(*(const f32x4*)s1, *(const f32x4*)(s1 + 4));
    }
#pragma unroll
    for (int nt = 0; nt < 4; ++nt) {
      short8 fwp[9];
#pragma unroll
      for (int s = 0; s < 9; ++s) fwp[s] = fpg[(nt*9 + s)*64];
#pragma unroll
      for (int s = 0; s < 9; ++s) {
        racc[0][nt] = MFMA(av0[s], fwp[s], racc[0][nt]);
        racc[1][nt] = MFMA(av1[s], fwp[s], racc[1][nt]);
      }
    }
  }
#pragma unroll
  for (int nt = 0; nt < 4; ++nt) {
    int n = nt*16 + cl;
    float bias = bp[n];
#pragma unroll
    for (int m = 0; m < 2; ++m)
#pragma unroll
      for (int r4 = 0; r4 < 4; ++r4)
        featL[2*2304 + (m*16 + g*4 + r4)*72 + n] = sbf(racc[m][nt][r4] + bias);
  }
  bt_write(btL, nb, lane);

  // ---- main DFS loop, zero barriers ----
#pragma unroll 1
  for (int p = 0; p < NJ; ++p) {
    const int j  = ORD[p];
    const int ps = PSL[p];
    const int ss = SSL[p];

    // A1 fragments for both m-tiles (x = [bt13|pad|feat64|pad])
    const short* fb0 = featL + ps*2304 + cl*72;
    const short* fb1 = featL + ps*2304 + (16 + cl)*72;
    short8 a0[2], a1[2], a2[2];
    a0[0] = (g < 2) ? *(const short8*)(btL + cl*24 + g*8)
                    : *(const short8*)(fb0 + (g-2)*8);
    a0[1] = (g < 2) ? *(const short8*)(btL + (16+cl)*24 + g*8)
                    : *(const short8*)(fb1 + (g-2)*8);
    a1[0] = *(const short8*)(fb0 + 16 + g*8);
    a1[1] = *(const short8*)(fb1 + 16 + g*8);
    a2[0] = (g < 2) ? *(const short8*)(fb0 + 48 + g*8) : zz;
    a2[1] = (g < 2) ? *(const short8*)(fb1 + 48 + g*8) : zz;

    if (p < NJ-1) nb = bt_load(pose, rel, rw0, ORD[p+1], lane);  // early issue

    // GEMM1: 5 n-tiles x K'=96, each weight fragment feeds both m-tiles
    f32x4 acc1[2][5] = {};
#pragma unroll
    for (int nt = 0; nt < 5; ++nt) {
      short8 w0 = f1g[(size_t)j*960 + (nt*3+0)*64];
      short8 w1 = f1g[(size_t)j*960 + (nt*3+1)*64];
      short8 w2 = f1g[(size_t)j*960 + (nt*3+2)*64];
      acc1[0][nt] = MFMA(a0[0], w0, acc1[0][nt]);
      acc1[1][nt] = MFMA(a0[1], w0, acc1[1][nt]);
      acc1[0][nt] = MFMA(a1[0], w1, acc1[0][nt]);
      acc1[1][nt] = MFMA(a1[1], w1, acc1[1][nt]);
      acc1[0][nt] = MFMA(a2[0], w2, acc1[0][nt]);
      acc1[1][nt] = MFMA(a2[1], w2, acc1[1][nt]);
    }
    // h epilogue -> LDS (wave-private)
    const float* b1i = b1 + j*77;
#pragma unroll
    for (int nt = 0; nt < 5; ++nt) {
      int n = nt*16 + cl;
      float bias = (n < 77) ? b1i[n] : 0.f;
#pragma unroll
      for (int m = 0; m < 2; ++m)
#pragma unroll
        for (int r4 = 0; r4 < 4; ++r4)
          hL[(m*16 + g*4 + r4)*80 + n] = sbf(fmaxf(acc1[m][nt][r4] + bias, 0.f));
    }
    // GEMM2 fragments
    short8 h0[2], h1[2], h2[2];
#pragma unroll
    for (int m = 0; m < 2; ++m) {
      const short* hb = hL + (m*16 + cl)*80;
      h0[m] = *(const short8*)(hb + g*8);
      h1[m] = *(const short8*)(hb + 32 + g*8);
      h2[m] = (g < 2) ? *(const short8*)(hb + 64 + g*8) : zz;
    }
    f32x4 acc2[2][4] = {};
#pragma unroll
    for (int nt = 0; nt < 4; ++nt) {
      short8 w0 = f2g[(size_t)j*768 + (nt*3+0)*64];
      short8 w1 = f2g[(size_t)j*768 + (nt*3+1)*64];
      short8 w2 = f2g[(size_t)j*768 + (nt*3+2)*64];
      acc2[0][nt] = MFMA(h0[0], w0, acc2[0][nt]);
      acc2[1][nt] = MFMA(h0[1], w0, acc2[1][nt]);
      acc2[0][nt] = MFMA(h1[0], w1, acc2[0][nt]);
      acc2[1][nt] = MFMA(h1[1], w1, acc2[1][nt]);
      acc2[0][nt] = MFMA(h2[0], w2, acc2[0][nt]);
      acc2[1][nt] = MFMA(h2[1], w2, acc2[1][nt]);
    }
    if (p < NJ-1) bt_write(btL, nb, lane);           // late write (T14 split)

    // out (nontemporal f32) + feat epilogue
    const float* b2i = b2 + j*64;
#pragma unroll
    for (int nt = 0; nt < 4; ++nt) {
      int n = nt*16 + cl;
      float bias = b2i[n];
#pragma unroll
      for (int m = 0; m < 2; ++m) {
        float* outb = out + (size_t)(rw0 + m*16 + g*4)*1536 + (size_t)j*64;
#pragma unroll
        for (int r4 = 0; r4 < 4; ++r4) {
          float v = fmaxf(acc2[m][nt][r4] + bias, 0.f);
          __builtin_nontemporal_store(v, &outb[(size_t)r4*1536 + n]);
          if (ss >= 0) featL[ss*2304 + (m*16 + g*4 + r4)*72 + n] = sbf(v);
        }
      }
    }
  }
}

extern "C" void kernel_launch(void* const* d_in, const int* in_sizes, int n_in,
                              void* d_out, int out_size, void* d_ws, size_t ws_size,
                              hipStream_t stream) {
  const float* pose = (const float*)d_in[0];
  const float* rel  = (const float*)d_in[1];
  const float* Wp   = (const float*)d_in[2];
  const float* bp   = (const float*)d_in[3];
  const float* W1   = (const float*)d_in[4];
  const float* b1   = (const float*)d_in[5];
  const float* W2   = (const float*)d_in[6];
  const float* b2   = (const float*)d_in[7];
  float* outp = (float*)d_out;
  short* img  = (short*)d_ws;            // 700,416 B scratch
  const int Bn = in_sizes[0] / 216;
  prep_kernel<<<(IMG_SHORTS + 255)/256, 256, 0, stream>>>(W1, W2, Wp, img);
  enc_kernel<<<Bn/128, 256, 0, stream>>>(pose, rel, bp, b1, b2, img, outp);
}

// Round 9
// 155.302 us; speedup vs baseline: 1.8353x; 1.3715x over previous
//
#include <hip/hip_runtime.h>
#include <hip/hip_bf16.h>
#include <math.h>

typedef __attribute__((ext_vector_type(8))) short short8;
typedef __attribute__((ext_vector_type(4))) float f32x4;

#define NJ 24

// ---- ws image: per-fragment 1KB blocks (64 lanes x 16B), lane-major ----
#define F1_J   7680
#define F2_OFF (NJ*F1_J)
#define F2_J   6144
#define FP_OFF (F2_OFF + NJ*F2_J)
#define IMG_SHORTS (FP_OFF + 36*512)        // 350208 shorts = 700416 B

#define MFMA(A,B,C) __builtin_amdgcn_mfma_f32_16x16x32_bf16((A),(B),(C),0,0,0)

__constant__ int ORD[24] = {0,1,4,7,10, 2,5,8,11, 3,6,9, 12,15, 13,16,18,20,22, 14,17,19,21,23};
__constant__ int PSL[24] = {2,0,1,1,1,  0,1,1,1,  0,0,0,  0,1,   0,1,1,1,1,    0,0,0,0,0};
__constant__ int SSL[24] = {0,1,1,1,-1, 1,1,1,-1, 0,0,0,  1,-1,  1,1,1,1,-1,   0,0,0,0,-1};

__device__ __forceinline__ short f2bf(float f) {
  union { float f; unsigned u; } v; v.f = f;
  unsigned r = v.u + 0x7FFFu + ((v.u >> 16) & 1u);
  return (short)(r >> 16);
}
__device__ __forceinline__ short sbf(float f) {
  __hip_bfloat16 h = __float2bfloat16(f);
  return *reinterpret_cast<short*>(&h);
}
__device__ __forceinline__ short8 pk8(f32x4 lo, f32x4 hi) {
  union { short8 s; unsigned u[4]; } r;
  asm("v_cvt_pk_bf16_f32 %0, %1, %2" : "=v"(r.u[0]) : "v"(lo[0]), "v"(lo[1]));
  asm("v_cvt_pk_bf16_f32 %0, %1, %2" : "=v"(r.u[1]) : "v"(lo[2]), "v"(lo[3]));
  asm("v_cvt_pk_bf16_f32 %0, %1, %2" : "=v"(r.u[2]) : "v"(hi[0]), "v"(hi[1]));
  asm("v_cvt_pk_bf16_f32 %0, %1, %2" : "=v"(r.u[3]) : "v"(hi[2]), "v"(hi[3]));
  return r.s;
}

__global__ __launch_bounds__(256) void prep_kernel(
    const float* __restrict__ W1, const float* __restrict__ W2,
    const float* __restrict__ Wp, short* __restrict__ img) {
  int t = blockIdx.x * 256 + threadIdx.x;
  if (t >= IMG_SHORTS) return;
  float v = 0.f;
  if (t < F2_OFF) {
    int i = t / F1_J, r = t % F1_J;
    int blk = r >> 9, q = r & 511;
    int ln = q >> 3, e = q & 7;
    int nt = blk / 3, s = blk - nt*3;
    int n  = nt*16 + (ln & 15);
    int kp = s*32 + (ln >> 4)*8 + e;
    if (n < 77) {
      if (kp < 13)                  v = W1[i*5929 + kp*77 + n];
      else if (kp >= 16 && kp < 80) v = W1[i*5929 + (kp-3)*77 + n];
    }
  } else if (t < FP_OFF) {
    int u = t - F2_OFF;
    int i = u / F2_J, r = u % F2_J;
    int blk = r >> 9, q = r & 511;
    int ln = q >> 3, e = q & 7;
    int nt = blk / 3, s = blk - nt*3;
    int n  = nt*16 + (ln & 15);
    int k  = s*32 + (ln >> 4)*8 + e;
    if (k < 77) v = W2[i*4928 + k*64 + n];
  } else {
    int u = t - FP_OFF;
    int blk = u >> 9, q = u & 511;
    int ln = q >> 3, e = q & 7;
    int nt = blk / 9, s = blk - nt*9;
    int n  = nt*16 + (ln & 15);
    int kp = s*32 + (ln >> 4)*8 + e;
    int j, w;
    if (kp < 216) { j = kp / 9;       w = kp % 9; }
    else          { j = (kp-216) / 3; w = 9 + (kp-216) % 3; }
    v = Wp[(j*12 + w)*64 + n];
  }
  img[t] = f2bf(v);
}

struct BT { float p0,p1,p2,p3,p4,p5,p6,p7; };
__device__ __forceinline__ BT bt_load(const float* __restrict__ pose,
                                      const float* __restrict__ rel,
                                      int rw0, int jj, int lane) {
  int r = lane >> 1, q = lane & 1;
  const float* pb = pose + (size_t)(rw0 + r)*216 + (size_t)jj*9;
  const float* rb = rel  + (size_t)(rw0 + r)*72  + (size_t)jj*3;
  BT b;
  if (q == 0) { b.p0=pb[0]; b.p1=pb[1]; b.p2=pb[2]; b.p3=pb[3];
                b.p4=pb[4]; b.p5=pb[5]; b.p6=pb[6]; b.p7=pb[7]; }
  else        { b.p0=pb[8]; b.p1=rb[0]; b.p2=rb[1]; b.p3=rb[2];
                b.p4=0;     b.p5=0;     b.p6=0;     b.p7=0; }
  return b;
}
__device__ __forceinline__ void bt_write(short* btL, BT b, int lane) {
  int r = lane >> 1, q = lane & 1;
  short8 w;
  if (q == 0) {
    w[0]=sbf(b.p0); w[1]=sbf(b.p1); w[2]=sbf(b.p2); w[3]=sbf(b.p3);
    w[4]=sbf(b.p4); w[5]=sbf(b.p5); w[6]=sbf(b.p6); w[7]=sbf(b.p7);
  } else {
    float nv = sqrtf(b.p1*b.p1 + b.p2*b.p2 + b.p3*b.p3);
    w[0]=sbf(b.p0); w[1]=sbf(b.p1); w[2]=sbf(b.p2); w[3]=sbf(b.p3);
    w[4]=sbf(nv);   w[5]=0; w[6]=0; w[7]=0;
  }
  *(short8*)(btL + r*24 + q*8) = w;
}

// issue 15 W1 fragment loads (asm-pinned, stay in flight across a GEMM phase)
#define ISSUE_W1(JN) do { \
  unsigned long long _b = img_u + (unsigned long long)(JN)*15360ull; \
  asm volatile( \
    "global_load_dwordx4 %0, %15, %16\n"  "global_load_dwordx4 %1, %15, %16 offset:1024\n" \
    "global_load_dwordx4 %2, %15, %16 offset:2048\n" "global_load_dwordx4 %3, %15, %16 offset:3072\n" \
    "global_load_dwordx4 %4, %15, %17\n"  "global_load_dwordx4 %5, %15, %17 offset:1024\n" \
    "global_load_dwordx4 %6, %15, %17 offset:2048\n" "global_load_dwordx4 %7, %15, %17 offset:3072\n" \
    "global_load_dwordx4 %8, %15, %18\n"  "global_load_dwordx4 %9, %15, %18 offset:1024\n" \
    "global_load_dwordx4 %10, %15, %18 offset:2048\n" "global_load_dwordx4 %11, %15, %18 offset:3072\n" \
    "global_load_dwordx4 %12, %15, %19\n" "global_load_dwordx4 %13, %15, %19 offset:1024\n" \
    "global_load_dwordx4 %14, %15, %19 offset:2048\n" \
    : "=v"(fw1[0]),"=v"(fw1[1]),"=v"(fw1[2]),"=v"(fw1[3]),"=v"(fw1[4]), \
      "=v"(fw1[5]),"=v"(fw1[6]),"=v"(fw1[7]),"=v"(fw1[8]),"=v"(fw1[9]), \
      "=v"(fw1[10]),"=v"(fw1[11]),"=v"(fw1[12]),"=v"(fw1[13]),"=v"(fw1[14]) \
    : "v"(voff), "s"(_b), "s"(_b+4096ull), "s"(_b+8192ull), "s"(_b+12288ull) \
    : "memory"); \
} while(0)

#define ISSUE_W2(J) do { \
  unsigned long long _b = img_u + 368640ull + (unsigned long long)(J)*12288ull; \
  asm volatile( \
    "global_load_dwordx4 %0, %12, %13\n"  "global_load_dwordx4 %1, %12, %13 offset:1024\n" \
    "global_load_dwordx4 %2, %12, %13 offset:2048\n" "global_load_dwordx4 %3, %12, %13 offset:3072\n" \
    "global_load_dwordx4 %4, %12, %14\n"  "global_load_dwordx4 %5, %12, %14 offset:1024\n" \
    "global_load_dwordx4 %6, %12, %14 offset:2048\n" "global_load_dwordx4 %7, %12, %14 offset:3072\n" \
    "global_load_dwordx4 %8, %12, %15\n"  "global_load_dwordx4 %9, %12, %15 offset:1024\n" \
    "global_load_dwordx4 %10, %12, %15 offset:2048\n" "global_load_dwordx4 %11, %12, %15 offset:3072\n" \
    : "=v"(fw2[0]),"=v"(fw2[1]),"=v"(fw2[2]),"=v"(fw2[3]),"=v"(fw2[4]),"=v"(fw2[5]), \
      "=v"(fw2[6]),"=v"(fw2[7]),"=v"(fw2[8]),"=v"(fw2[9]),"=v"(fw2[10]),"=v"(fw2[11]) \
    : "v"(voff), "s"(_b), "s"(_b+4096ull), "s"(_b+8192ull) \
    : "memory"); \
} while(0)

#define WAITV(N) do { asm volatile("s_waitcnt vmcnt(" #N ")" ::: "memory"); \
                      __builtin_amdgcn_sched_barrier(0); } while(0)

// 256 threads = 4 waves; wave owns 32 rows + whole tree. ZERO barriers.
// Per-wave LDS: feat 3x[32][68] | h [32][84] | bt [32][24] = 19,968 B
__global__ __launch_bounds__(256, 2) void enc_kernel(
    const float* __restrict__ pose, const float* __restrict__ rel,
    const float* __restrict__ bp,  const float* __restrict__ b1,
    const float* __restrict__ b2,  const short* __restrict__ img,
    float* __restrict__ out) {
  __shared__ __align__(16) short lds[4*9984];        // 79,872 B -> 2 WG/CU

  const int tid  = threadIdx.x;
  const int lane = tid & 63;
  const int wv   = tid >> 6;
  short* myl   = lds + wv*9984;
  short* featL = myl;                                // 3 x [32][68] = 6528
  short* hL    = myl + 6528;                         // [32][84]
  short* btL   = myl + 9216;                         // [32][24]

  const int cl  = lane & 15;
  const int g   = lane >> 4;
  const int rw0 = blockIdx.x*128 + wv*32;
  const short8 zz = {0,0,0,0,0,0,0,0};
  const unsigned long long img_u = (unsigned long long)img;
  const unsigned voff = (unsigned)lane << 4;

  short8 fw1[15], fw2[12];

  // ---- prologue: bt[joint 0] loads, W1[0] asm issue, root GEMM ----
  BT nb = bt_load(pose, rel, rw0, 0, lane);
  ISSUE_W1(0);

  f32x4 racc[2][4] = {};
  {
    const float* pr0 = pose + (size_t)(rw0 + cl)*216;
    const float* rr0 = rel  + (size_t)(rw0 + cl)*72;
    const float* pr1 = pose + (size_t)(rw0 + 16 + cl)*216;
    const float* rr1 = rel  + (size_t)(rw0 + 16 + cl)*72;
    const short8* fpg = (const short8*)(img + FP_OFF) + lane;
    short8 av0[9], av1[9];
#pragma unroll
    for (int s = 0; s < 9; ++s) {
      int k0 = s*32 + g*8;
      const float* s0 = (k0 < 216) ? (pr0 + k0) : (rr0 + (k0 - 216));
      const float* s1 = (k0 < 216) ? (pr1 + k0) : (rr1 + (k0 - 216));
      av0[s] = pk8(*(const f32x4*)s0, *(const f32x4*)(s0 + 4));
      av1[s] = pk8(*(const f32x4*)s1, *(const f32x4*)(s1 + 4));
    }
#pragma unroll
    for (int nt = 0; nt < 4; ++nt) {
      short8 fwp[9];
#pragma unroll
      for (int s = 0; s < 9; ++s) fwp[s] = fpg[(nt*9 + s)*64];
#pragma unroll
      for (int s = 0; s < 9; ++s) {
        racc[0][nt] = MFMA(av0[s], fwp[s], racc[0][nt]);
        racc[1][nt] = MFMA(av1[s], fwp[s], racc[1][nt]);
      }
    }
  }
#pragma unroll
  for (int nt = 0; nt < 4; ++nt) {
    int n = nt*16 + cl;
    float bias = bp[n];
#pragma unroll
    for (int m = 0; m < 2; ++m)
#pragma unroll
      for (int r4 = 0; r4 < 4; ++r4)
        featL[2*2176 + (m*16 + g*4 + r4)*68 + n] = sbf(racc[m][nt][r4] + bias);
  }
  bt_write(btL, nb, lane);

  // ---- main DFS loop, zero barriers, asm-pinned weight pipeline ----
#pragma unroll 1
  for (int p = 0; p < NJ; ++p) {
    const int j  = ORD[p];
    const int ps = PSL[p];
    const int ss = SSL[p];
    const int jn = (p < NJ-1) ? ORD[p+1] : 0;

    // B: inputs pinned BEFORE the W2 issue (keeps vmcnt counts exact)
    if (p < NJ-1) nb = bt_load(pose, rel, rw0, jn, lane);
    float bl1[5], bl2[4];
#pragma unroll
    for (int nt = 0; nt < 5; ++nt) {
      int n = nt*16 + cl;
      bl1[nt] = (n < 77) ? b1[j*77 + n] : 0.f;
    }
#pragma unroll
    for (int nt = 0; nt < 4; ++nt) bl2[nt] = b2[j*64 + nt*16 + cl];

    const short* fb0 = featL + ps*2176 + cl*68;
    const short* fb1 = featL + ps*2176 + (16 + cl)*68;
    short8 a0[2], a1[2], a2[2];
    a0[0] = (g < 2) ? *(const short8*)(btL + cl*24 + g*8)
                    : *(const short8*)(fb0 + (g-2)*8);
    a0[1] = (g < 2) ? *(const short8*)(btL + (16+cl)*24 + g*8)
                    : *(const short8*)(fb1 + (g-2)*8);
    a1[0] = *(const short8*)(fb0 + 16 + g*8);
    a1[1] = *(const short8*)(fb1 + 16 + g*8);
    a2[0] = (g < 2) ? *(const short8*)(fb0 + 48 + g*8) : zz;
    a2[1] = (g < 2) ? *(const short8*)(fb1 + 48 + g*8) : zz;

    ISSUE_W2(j);          // A: 12 newest VMEM ops from here on
    WAITV(12);            // C: all but the 12 W2 loads done -> fw1 ready

    // D: GEMM1, per-nt acc freeing
#pragma unroll
    for (int nt = 0; nt < 5; ++nt) {
      f32x4 c0 = {0,0,0,0}, c1 = {0,0,0,0};
      c0 = MFMA(a0[0], fw1[nt*3+0], c0);  c1 = MFMA(a0[1], fw1[nt*3+0], c1);
      c0 = MFMA(a1[0], fw1[nt*3+1], c0);  c1 = MFMA(a1[1], fw1[nt*3+1], c1);
      c0 = MFMA(a2[0], fw1[nt*3+2], c0);  c1 = MFMA(a2[1], fw1[nt*3+2], c1);
      int n = nt*16 + cl;
#pragma unroll
      for (int r4 = 0; r4 < 4; ++r4) {
        hL[(g*4 + r4)*84 + n]      = sbf(fmaxf(c0[r4] + bl1[nt], 0.f));
        hL[(16 + g*4 + r4)*84 + n] = sbf(fmaxf(c1[r4] + bl1[nt], 0.f));
      }
    }
    // E: h fragments + bt_write (pre-F so compiler waits can't drain W1[jn])
    short8 h0[2], h1[2], h2[2];
#pragma unroll
    for (int m = 0; m < 2; ++m) {
      const short* hb = hL + (m*16 + cl)*84;
      h0[m] = *(const short8*)(hb + g*8);
      h1[m] = *(const short8*)(hb + 32 + g*8);
      h2[m] = (g < 2) ? *(const short8*)(hb + 64 + g*8) : zz;
    }
    if (p < NJ-1) bt_write(btL, nb, lane);

    if (p < NJ-1) { ISSUE_W1(jn); WAITV(15); }   // F,H: fw2 ready, W1[jn] in flight
    else          { WAITV(0); }

    // I: GEMM2 per-nt + epilogue
#pragma unroll
    for (int nt = 0; nt < 4; ++nt) {
      f32x4 c0 = {0,0,0,0}, c1 = {0,0,0,0};
      c0 = MFMA(h0[0], fw2[nt*3+0], c0);  c1 = MFMA(h0[1], fw2[nt*3+0], c1);
      c0 = MFMA(h1[0], fw2[nt*3+1], c0);  c1 = MFMA(h1[1], fw2[nt*3+1], c1);
      c0 = MFMA(h2[0], fw2[nt*3+2], c0);  c1 = MFMA(h2[1], fw2[nt*3+2], c1);
      int n = nt*16 + cl;
#pragma unroll
      for (int m = 0; m < 2; ++m) {
        f32x4& cc = m ? c1 : c0;
        float* outb = out + (size_t)(rw0 + m*16 + g*4)*1536 + (size_t)j*64;
#pragma unroll
        for (int r4 = 0; r4 < 4; ++r4) {
          float v = fmaxf(cc[r4] + bl2[nt], 0.f);
          __builtin_nontemporal_store(v, &outb[(size_t)r4*1536 + n]);
          if (ss >= 0) featL[ss*2176 + (m*16 + g*4 + r4)*68 + n] = sbf(v);
        }
      }
    }
  }
}

extern "C" void kernel_launch(void* const* d_in, const int* in_sizes, int n_in,
                              void* d_out, int out_size, void* d_ws, size_t ws_size,
                              hipStream_t stream) {
  const float* pose = (const float*)d_in[0];
  const float* rel  = (const float*)d_in[1];
  const float* Wp   = (const float*)d_in[2];
  const float* bp   = (const float*)d_in[3];
  const float* W1   = (const float*)d_in[4];
  const float* b1   = (const float*)d_in[5];
  const float* W2   = (const float*)d_in[6];
  const float* b2   = (const float*)d_in[7];
  float* outp = (float*)d_out;
  short* img  = (short*)d_ws;
  const int Bn = in_sizes[0] / 216;
  prep_kernel<<<(IMG_SHORTS + 255)/256, 256, 0, stream>>>(W1, W2, Wp, img);
  enc_kernel<<<Bn/128, 256, 0, stream>>>(pose, rel, bp, b1, b2, img, outp);
}

// Round 11
// 154.368 us; speedup vs baseline: 1.8464x; 1.0061x over previous
//
#include <hip/hip_runtime.h>
#include <hip/hip_bf16.h>
#include <math.h>

typedef __attribute__((ext_vector_type(8))) short short8;
typedef __attribute__((ext_vector_type(4))) float f32x4;

#define NJ 24

// ---- ws image: per-fragment 1KB blocks (64 lanes x 16B), lane-major ----
// W1image row 13 = b1 (bias-as-K: x[13]=1), row13 col77 = 1.0 (h[77] regenerator)
// W2image row 77 = b2
#define F1_J   7680
#define F2_OFF (NJ*F1_J)
#define F2_J   6144
#define FP_OFF (F2_OFF + NJ*F2_J)
#define IMG_SHORTS (FP_OFF + 36*512)        // 350208 shorts = 700416 B

#define MFMA(A,B,C) __builtin_amdgcn_mfma_f32_16x16x32_bf16((A),(B),(C),0,0,0)

__constant__ int ORD[24] = {0,1,4,7,10, 2,5,8,11, 3,6,9, 12,15, 13,16,18,20,22, 14,17,19,21,23};
__constant__ int PSL[24] = {2,0,1,1,1,  0,1,1,1,  0,0,0,  0,1,   0,1,1,1,1,    0,0,0,0,0};
__constant__ int SSL[24] = {0,1,1,1,-1, 1,1,1,-1, 0,0,0,  1,-1,  1,1,1,1,-1,   0,0,0,0,-1};

__device__ __forceinline__ short f2bf(float f) {
  union { float f; unsigned u; } v; v.f = f;
  unsigned r = v.u + 0x7FFFu + ((v.u >> 16) & 1u);
  return (short)(r >> 16);
}
__device__ __forceinline__ short sbf(float f) {
  __hip_bfloat16 h = __float2bfloat16(f);
  return *reinterpret_cast<short*>(&h);
}
__device__ __forceinline__ short8 pk8(f32x4 lo, f32x4 hi) {
  union { short8 s; unsigned u[4]; } r;
  asm("v_cvt_pk_bf16_f32 %0, %1, %2" : "=v"(r.u[0]) : "v"(lo[0]), "v"(lo[1]));
  asm("v_cvt_pk_bf16_f32 %0, %1, %2" : "=v"(r.u[1]) : "v"(lo[2]), "v"(lo[3]));
  asm("v_cvt_pk_bf16_f32 %0, %1, %2" : "=v"(r.u[2]) : "v"(hi[0]), "v"(hi[1]));
  asm("v_cvt_pk_bf16_f32 %0, %1, %2" : "=v"(r.u[3]) : "v"(hi[2]), "v"(hi[3]));
  return r.s;
}

__global__ __launch_bounds__(256) void prep_kernel(
    const float* __restrict__ W1, const float* __restrict__ W2,
    const float* __restrict__ Wp, const float* __restrict__ b1,
    const float* __restrict__ b2, short* __restrict__ img) {
  int t = blockIdx.x * 256 + threadIdx.x;
  if (t >= IMG_SHORTS) return;
  float v = 0.f;
  if (t < F2_OFF) {
    int i = t / F1_J, r = t % F1_J;
    int blk = r >> 9, q = r & 511;
    int ln = q >> 3, e = q & 7;
    int nt = blk / 3, s = blk - nt*3;
    int n  = nt*16 + (ln & 15);
    int kp = s*32 + (ln >> 4)*8 + e;
    if (kp == 13) {                       // bias row (x[13] = 1)
      v = (n < 77) ? b1[i*77 + n] : (n == 77 ? 1.f : 0.f);
    } else if (n < 77) {
      if (kp < 13)                  v = W1[i*5929 + kp*77 + n];
      else if (kp >= 16 && kp < 80) v = W1[i*5929 + (kp-3)*77 + n];
    }
  } else if (t < FP_OFF) {
    int u = t - F2_OFF;
    int i = u / F2_J, r = u % F2_J;
    int blk = r >> 9, q = r & 511;
    int ln = q >> 3, e = q & 7;
    int nt = blk / 3, s = blk - nt*3;
    int n  = nt*16 + (ln & 15);
    int k  = s*32 + (ln >> 4)*8 + e;
    if (k < 77)       v = W2[i*4928 + k*64 + n];
    else if (k == 77) v = b2[i*64 + n];   // bias row (h[77] = 1)
  } else {
    int u = t - FP_OFF;
    int blk = u >> 9, q = u & 511;
    int ln = q >> 3, e = q & 7;
    int nt = blk / 9, s = blk - nt*9;
    int n  = nt*16 + (ln & 15);
    int kp = s*32 + (ln >> 4)*8 + e;
    int j, w;
    if (kp < 216) { j = kp / 9;       w = kp % 9; }
    else          { j = (kp-216) / 3; w = 9 + (kp-216) % 3; }
    v = Wp[(j*12 + w)*64 + n];
  }
  img[t] = f2bf(v);
}

// 15 W1 fragment loads (asm-pinned, 16B-aligned, in-bounds)
#define ISSUE_W1(JN) do { \
  unsigned long long _b = img_u + (unsigned long long)(JN)*15360ull; \
  asm volatile( \
    "global_load_dwordx4 %0, %15, %16\n"  "global_load_dwordx4 %1, %15, %16 offset:1024\n" \
    "global_load_dwordx4 %2, %15, %16 offset:2048\n" "global_load_dwordx4 %3, %15, %16 offset:3072\n" \
    "global_load_dwordx4 %4, %15, %17\n"  "global_load_dwordx4 %5, %15, %17 offset:1024\n" \
    "global_load_dwordx4 %6, %15, %17 offset:2048\n" "global_load_dwordx4 %7, %15, %17 offset:3072\n" \
    "global_load_dwordx4 %8, %15, %18\n"  "global_load_dwordx4 %9, %15, %18 offset:1024\n" \
    "global_load_dwordx4 %10, %15, %18 offset:2048\n" "global_load_dwordx4 %11, %15, %18 offset:3072\n" \
    "global_load_dwordx4 %12, %15, %19\n" "global_load_dwordx4 %13, %15, %19 offset:1024\n" \
    "global_load_dwordx4 %14, %15, %19 offset:2048\n" \
    : "=&v"(fw1[0]),"=&v"(fw1[1]),"=&v"(fw1[2]),"=&v"(fw1[3]),"=&v"(fw1[4]), \
      "=&v"(fw1[5]),"=&v"(fw1[6]),"=&v"(fw1[7]),"=&v"(fw1[8]),"=&v"(fw1[9]), \
      "=&v"(fw1[10]),"=&v"(fw1[11]),"=&v"(fw1[12]),"=&v"(fw1[13]),"=&v"(fw1[14]) \
    : "v"(voff), "s"(_b), "s"(_b+4096ull), "s"(_b+8192ull), "s"(_b+12288ull) \
    : "memory"); \
} while(0)

// 8 bt dword loads (4B-aligned, in-bounds for every row/joint) + 12 W2 x4 loads.
// Census: 20. aA/vB computed in C before the block.
#define ISSUE_BTW2(J) do { \
  unsigned long long _b = img_u + 368640ull + (unsigned long long)(J)*12288ull; \
  asm volatile( \
    "global_load_dword %0, %20, off\n" \
    "global_load_dword %1, %20, off offset:4\n" \
    "global_load_dword %2, %20, off offset:8\n" \
    "global_load_dword %3, %20, off offset:12\n" \
    "global_load_dword %4, %21, %22\n" \
    "global_load_dword %5, %21, %22 offset:4\n" \
    "global_load_dword %6, %21, %22 offset:8\n" \
    "global_load_dword %7, %21, %22 offset:12\n" \
    "global_load_dwordx4 %8, %23, %24\n"  "global_load_dwordx4 %9, %23, %24 offset:1024\n" \
    "global_load_dwordx4 %10, %23, %24 offset:2048\n" "global_load_dwordx4 %11, %23, %24 offset:3072\n" \
    "global_load_dwordx4 %12, %23, %25\n" "global_load_dwordx4 %13, %23, %25 offset:1024\n" \
    "global_load_dwordx4 %14, %23, %25 offset:2048\n" "global_load_dwordx4 %15, %23, %25 offset:3072\n" \
    "global_load_dwordx4 %16, %23, %26\n" "global_load_dwordx4 %17, %23, %26 offset:1024\n" \
    "global_load_dwordx4 %18, %23, %26 offset:2048\n" "global_load_dwordx4 %19, %23, %26 offset:3072\n" \
    : "=&v"(d0),"=&v"(d1),"=&v"(d2),"=&v"(d3),"=&v"(d4),"=&v"(d5),"=&v"(d6),"=&v"(d7), \
      "=&v"(fw2[0]),"=&v"(fw2[1]),"=&v"(fw2[2]),"=&v"(fw2[3]),"=&v"(fw2[4]),"=&v"(fw2[5]), \
      "=&v"(fw2[6]),"=&v"(fw2[7]),"=&v"(fw2[8]),"=&v"(fw2[9]),"=&v"(fw2[10]),"=&v"(fw2[11]) \
    : "v"(aA), "v"(vB), "s"(pose_u), "v"(voff), \
      "s"(_b), "s"(_b+4096ull), "s"(_b+8192ull) \
    : "memory"); \
} while(0)

#define WAITV(N) do { asm volatile("s_waitcnt vmcnt(" #N ")" ::: "memory"); \
                      __builtin_amdgcn_sched_barrier(0); } while(0)

// 256 threads = 4 waves; wave owns 32 rows + whole tree. ZERO barriers.
// ZERO compiler VMEM in the main loop -> exact vmcnt census:
//   I:32 stores | A:20 (bt8+W2x4*12) | F:15 (W1 next)
//   C waits 52 (retire W1[j], stores+bt/W2 in flight); H waits 15.
__global__ __launch_bounds__(256, 2) void enc_kernel(
    const float* __restrict__ pose, const float* __restrict__ rel,
    const float* __restrict__ bp,  const short* __restrict__ img,
    float* __restrict__ out) {
  __shared__ __align__(16) short lds[4*10240];       // 81,920 B -> 2 WG/CU

  const int tid  = threadIdx.x;
  const int lane = tid & 63;
  const int wv   = tid >> 6;
  short* myl   = lds + wv*10240;
  short* featL = myl;                                // 3 x [32][72] = 6912
  short* hL    = myl + 6912;                         // [32][80] = 2560
  short* btL   = myl + 9472;                         // [32][24] = 768

  const int cl  = lane & 15;
  const int g   = lane >> 4;
  const int rw0 = blockIdx.x*128 + wv*32;
  const short8 zz = {0,0,0,0,0,0,0,0};
  const unsigned long long img_u  = (unsigned long long)img;
  const unsigned long long pose_u = (unsigned long long)pose;
  const unsigned long long rel_u  = (unsigned long long)rel;
  const unsigned voff = (unsigned)lane << 4;
  const int btr = lane >> 1, btq = lane & 1;
  const unsigned btProw = (unsigned)((rw0 + btr)*864);   // pose row byte base
  const unsigned btRrow = (unsigned)((rw0 + btr)*288);   // rel  row byte base

  short8 fw1[15], fw2[12];
  float d0, d1, d2, d3, d4, d5, d6, d7;

  // ---- prologue: bt[joint 0] via compiler loads (before any asm VMEM) ----
  {
    const float* pb = pose + (size_t)(rw0 + btr)*216;
    const float* rb = rel  + (size_t)(rw0 + btr)*72;
    short8 w;
    if (btq == 0) {
      w = pk8(*(const f32x4*)pb, *(const f32x4*)(pb + 4));
    } else {
      float r0 = rb[0], r1 = rb[1], r2 = rb[2];
      float nv = sqrtf(r0*r0 + r1*r1 + r2*r2);
      w[0]=sbf(pb[8]); w[1]=sbf(r0); w[2]=sbf(r1); w[3]=sbf(r2);
      w[4]=sbf(nv); w[5]=(short)0x3F80; w[6]=0; w[7]=0;   // col13 = 1.0
    }
    *(short8*)(btL + btr*24 + btq*8) = w;
  }

  // ---- root: bonefeat(32x288) @ WpT + bp -> feat slot 2 (compiler loads) ----
  f32x4 racc[2][4] = {};
  {
    const float* pr0 = pose + (size_t)(rw0 + cl)*216;
    const float* rr0 = rel  + (size_t)(rw0 + cl)*72;
    const float* pr1 = pose + (size_t)(rw0 + 16 + cl)*216;
    const float* rr1 = rel  + (size_t)(rw0 + 16 + cl)*72;
    const short8* fpg = (const short8*)(img + FP_OFF) + lane;
    short8 av0[9], av1[9];
#pragma unroll
    for (int s = 0; s < 9; ++s) {
      int k0 = s*32 + g*8;
      const float* s0 = (k0 < 216) ? (pr0 + k0) : (rr0 + (k0 - 216));
      const float* s1 = (k0 < 216) ? (pr1 + k0) : (rr1 + (k0 - 216));
      av0[s] = pk8(*(const f32x4*)s0, *(const f32x4*)(s0 + 4));
      av1[s] = pk8(*(const f32x4*)s1, *(const f32x4*)(s1 + 4));
    }
#pragma unroll
    for (int nt = 0; nt < 4; ++nt) {
      short8 fwp[9];
#pragma unroll
      for (int s = 0; s < 9; ++s) fwp[s] = fpg[(nt*9 + s)*64];
#pragma unroll
      for (int s = 0; s < 9; ++s) {
        racc[0][nt] = MFMA(av0[s], fwp[s], racc[0][nt]);
        racc[1][nt] = MFMA(av1[s], fwp[s], racc[1][nt]);
      }
    }
  }
#pragma unroll
  for (int nt = 0; nt < 4; ++nt) {
    int n = nt*16 + cl;
    float bias = bp[n];
#pragma unroll
    for (int m = 0; m < 2; ++m)
#pragma unroll
      for (int r4 = 0; r4 < 4; ++r4)
        featL[2*2304 + (m*16 + g*4 + r4)*72 + n] = sbf(racc[m][nt][r4] + bias);
  }

  ISSUE_W1(0);                                       // first asm VMEM; census 15

  // ---- main DFS loop ----
#pragma unroll 1
  for (int p = 0; p < NJ; ++p) {
    const int j  = ORD[p];
    const int ps = PSL[p];
    const int ss = SSL[p];
    const int jn = (p < NJ-1) ? ORD[p+1] : 0;        // dummy jn=0 on last iter

    // B: A-fragments from LDS (lgkm only)
    const short* fb0 = featL + ps*2304 + cl*72;
    const short* fb1 = featL + ps*2304 + (16 + cl)*72;
    short8 a0[2], a1[2], a2[2];
    a0[0] = (g < 2) ? *(const short8*)(btL + cl*24 + g*8)
                    : *(const short8*)(fb0 + (g-2)*8);
    a0[1] = (g < 2) ? *(const short8*)(btL + (16+cl)*24 + g*8)
                    : *(const short8*)(fb1 + (g-2)*8);
    a1[0] = *(const short8*)(fb0 + 16 + g*8);
    a1[1] = *(const short8*)(fb1 + 16 + g*8);
    a2[0] = (g < 2) ? *(const short8*)(fb0 + 48 + g*8) : zz;
    a2[1] = (g < 2) ? *(const short8*)(fb1 + 48 + g*8) : zz;

    // A: bt(jn) dwords + W2(j) x4s — all 4B-aligned, all in-bounds
    const unsigned long long aA =
        btq ? (rel_u  + btRrow + (unsigned)(jn ? jn*12 - 4 : 0))
            : (pose_u + btProw + (unsigned)(jn*36));
    const unsigned vB = btProw + (unsigned)(jn*36) + (btq ? 20u : 16u);
    ISSUE_BTW2(j);

    // C: retire W1[j] only (stores + bt/W2 stay in flight)
    if (p == 0) { WAITV(20); } else { WAITV(52); }

    // D: GEMM1 (bias folded into W1image row 13)
#pragma unroll
    for (int nt = 0; nt < 5; ++nt) {
      f32x4 c0 = {0,0,0,0}, c1 = {0,0,0,0};
      c0 = MFMA(a0[0], fw1[nt*3+0], c0);  c1 = MFMA(a0[1], fw1[nt*3+0], c1);
      c0 = MFMA(a1[0], fw1[nt*3+1], c0);  c1 = MFMA(a1[1], fw1[nt*3+1], c1);
      c0 = MFMA(a2[0], fw1[nt*3+2], c0);  c1 = MFMA(a2[1], fw1[nt*3+2], c1);
      int n = nt*16 + cl;
#pragma unroll
      for (int r4 = 0; r4 < 4; ++r4) {
        hL[(g*4 + r4)*80 + n]      = sbf(fmaxf(c0[r4], 0.f));
        hL[(16 + g*4 + r4)*80 + n] = sbf(fmaxf(c1[r4], 0.f));
      }
    }
    // E: h fragments (lgkm)
    short8 h0[2], h1[2], h2[2];
#pragma unroll
    for (int m = 0; m < 2; ++m) {
      const short* hb = hL + (m*16 + cl)*80;
      h0[m] = *(const short8*)(hb + g*8);
      h1[m] = *(const short8*)(hb + 32 + g*8);
      h2[m] = (g < 2) ? *(const short8*)(hb + 64 + g*8) : zz;  // incl h[77]=1 -> b2
    }

    ISSUE_W1(jn);                                    // F: census 15
    WAITV(15);                                       // H: retire stores + bt/W2

    // decode bt(jn) -> btL (col13 = 1.0)
    {
      f32x4 lo = {d0, d1, d2, d3}, hi = {d4, d5, d6, d7};
      short8 wA = pk8(lo, hi);                       // btq=0: pose f0..f7
      float r0 = jn ? d1 : d0;                       // btq=1: rel r0..r2
      float r1 = jn ? d2 : d1;
      float r2 = jn ? d3 : d2;
      float nv = sqrtf(r0*r0 + r1*r1 + r2*r2);
      short8 wB;
      wB[0]=sbf(d7);   wB[1]=sbf(r0); wB[2]=sbf(r1); wB[3]=sbf(r2);
      wB[4]=sbf(nv); wB[5]=(short)0x3F80; wB[6]=0; wB[7]=0;
      short8 w = btq ? wB : wA;
      *(short8*)(btL + btr*24 + btq*8) = w;
    }

    // I: GEMM2 (bias via h[77]=1 x W2row77) + 32 nt stores + feat writes
#pragma unroll
    for (int nt = 0; nt < 4; ++nt) {
      f32x4 c0 = {0,0,0,0}, c1 = {0,0,0,0};
      c0 = MFMA(h0[0], fw2[nt*3+0], c0);  c1 = MFMA(h0[1], fw2[nt*3+0], c1);
      c0 = MFMA(h1[0], fw2[nt*3+1], c0);  c1 = MFMA(h1[1], fw2[nt*3+1], c1);
      c0 = MFMA(h2[0], fw2[nt*3+2], c0);  c1 = MFMA(h2[1], fw2[nt*3+2], c1);
      int n = nt*16 + cl;
#pragma unroll
      for (int m = 0; m < 2; ++m) {
        f32x4& cc = m ? c1 : c0;
        float* outb = out + (size_t)(rw0 + m*16 + g*4)*1536 + (size_t)j*64;
#pragma unroll
        for (int r4 = 0; r4 < 4; ++r4) {
          float v = fmaxf(cc[r4], 0.f);
          __builtin_nontemporal_store(v, &outb[(size_t)r4*1536 + n]);
          if (ss >= 0) featL[ss*2304 + (m*16 + g*4 + r4)*72 + n] = sbf(v);
        }
      }
    }
  }
}

extern "C" void kernel_launch(void* const* d_in, const int* in_sizes, int n_in,
                              void* d_out, int out_size, void* d_ws, size_t ws_size,
                              hipStream_t stream) {
  const float* pose = (const float*)d_in[0];
  const float* rel  = (const float*)d_in[1];
  const float* Wp   = (const float*)d_in[2];
  const float* bp   = (const float*)d_in[3];
  const float* W1   = (const float*)d_in[4];
  const float* b1   = (const float*)d_in[5];
  const float* W2   = (const float*)d_in[6];
  const float* b2   = (const float*)d_in[7];
  float* outp = (float*)d_out;
  short* img  = (short*)d_ws;
  const int Bn = in_sizes[0] / 216;
  prep_kernel<<<(IMG_SHORTS + 255)/256, 256, 0, stream>>>(W1, W2, Wp, b1, b2, img);
  enc_kernel<<<Bn/128, 256, 0, stream>>>(pose, rel, bp, img, outp);
}

// Round 12
// 153.427 us; speedup vs baseline: 1.8577x; 1.0061x over previous
//
#include <hip/hip_runtime.h>
#include <hip/hip_bf16.h>
#include <math.h>

typedef __attribute__((ext_vector_type(8))) short short8;
typedef __attribute__((ext_vector_type(4))) short s4;
typedef __attribute__((ext_vector_type(4))) float f32x4;

#define NJ 24

// ---- ws image: per-fragment 1KB blocks (64 lanes x 16B), lane-major ----
// W1image row 13 = b1 (bias-as-K: x[13]=1), row13 col77 = 1.0 (h[77] regenerator)
// W2image row 77 = b2
#define F1_J   7680
#define F2_OFF (NJ*F1_J)
#define F2_J   6144
#define FP_OFF (F2_OFF + NJ*F2_J)
#define IMG_SHORTS (FP_OFF + 36*512)        // 350208 shorts = 700416 B

// operand-swapped MFMA: A = weights [n][k], B = activations [k][batch]
// C: col(lane&15)=batch row, row((lane>>4)*4+reg)=n  -> 4 consecutive n per lane
#define MFMA(A,B,C) __builtin_amdgcn_mfma_f32_16x16x32_bf16((A),(B),(C),0,0,0)

__constant__ int ORD[24] = {0,1,4,7,10, 2,5,8,11, 3,6,9, 12,15, 13,16,18,20,22, 14,17,19,21,23};
__constant__ int PSL[24] = {2,0,1,1,1,  0,1,1,1,  0,0,0,  0,1,   0,1,1,1,1,    0,0,0,0,0};
__constant__ int SSL[24] = {0,1,1,1,-1, 1,1,1,-1, 0,0,0,  1,-1,  1,1,1,1,-1,   0,0,0,0,-1};

__device__ __forceinline__ short f2bf(float f) {
  union { float f; unsigned u; } v; v.f = f;
  unsigned r = v.u + 0x7FFFu + ((v.u >> 16) & 1u);
  return (short)(r >> 16);
}
__device__ __forceinline__ short sbf(float f) {
  __hip_bfloat16 h = __float2bfloat16(f);
  return *reinterpret_cast<short*>(&h);
}
__device__ __forceinline__ short8 pk8(f32x4 lo, f32x4 hi) {
  union { short8 s; unsigned u[4]; } r;
  asm("v_cvt_pk_bf16_f32 %0, %1, %2" : "=v"(r.u[0]) : "v"(lo[0]), "v"(lo[1]));
  asm("v_cvt_pk_bf16_f32 %0, %1, %2" : "=v"(r.u[1]) : "v"(lo[2]), "v"(lo[3]));
  asm("v_cvt_pk_bf16_f32 %0, %1, %2" : "=v"(r.u[2]) : "v"(hi[0]), "v"(hi[1]));
  asm("v_cvt_pk_bf16_f32 %0, %1, %2" : "=v"(r.u[3]) : "v"(hi[2]), "v"(hi[3]));
  return r.s;
}
__device__ __forceinline__ s4 pk4(f32x4 v) {       // 4 f32 -> 4 bf16
  union { s4 s; unsigned u[2]; } r;
  asm("v_cvt_pk_bf16_f32 %0, %1, %2" : "=v"(r.u[0]) : "v"(v[0]), "v"(v[1]));
  asm("v_cvt_pk_bf16_f32 %0, %1, %2" : "=v"(r.u[1]) : "v"(v[2]), "v"(v[3]));
  return r.s;
}
__device__ __forceinline__ f32x4 relu4(f32x4 v) {
  f32x4 r; r[0]=fmaxf(v[0],0.f); r[1]=fmaxf(v[1],0.f);
  r[2]=fmaxf(v[2],0.f); r[3]=fmaxf(v[3],0.f); return r;
}

__global__ __launch_bounds__(256) void prep_kernel(
    const float* __restrict__ W1, const float* __restrict__ W2,
    const float* __restrict__ Wp, const float* __restrict__ b1,
    const float* __restrict__ b2, short* __restrict__ img) {
  int t = blockIdx.x * 256 + threadIdx.x;
  if (t >= IMG_SHORTS) return;
  float v = 0.f;
  if (t < F2_OFF) {
    int i = t / F1_J, r = t % F1_J;
    int blk = r >> 9, q = r & 511;
    int ln = q >> 3, e = q & 7;
    int nt = blk / 3, s = blk - nt*3;
    int n  = nt*16 + (ln & 15);
    int kp = s*32 + (ln >> 4)*8 + e;
    if (kp == 13) {                       // bias row (x[13] = 1)
      v = (n < 77) ? b1[i*77 + n] : (n == 77 ? 1.f : 0.f);
    } else if (n < 77) {
      if (kp < 13)                  v = W1[i*5929 + kp*77 + n];
      else if (kp >= 16 && kp < 80) v = W1[i*5929 + (kp-3)*77 + n];
    }
  } else if (t < FP_OFF) {
    int u = t - F2_OFF;
    int i = u / F2_J, r = u % F2_J;
    int blk = r >> 9, q = r & 511;
    int ln = q >> 3, e = q & 7;
    int nt = blk / 3, s = blk - nt*3;
    int n  = nt*16 + (ln & 15);
    int k  = s*32 + (ln >> 4)*8 + e;
    if (k < 77)       v = W2[i*4928 + k*64 + n];
    else if (k == 77) v = b2[i*64 + n];   // bias row (h[77] = 1)
  } else {
    int u = t - FP_OFF;
    int blk = u >> 9, q = u & 511;
    int ln = q >> 3, e = q & 7;
    int nt = blk / 9, s = blk - nt*9;
    int n  = nt*16 + (ln & 15);
    int kp = s*32 + (ln >> 4)*8 + e;
    int j, w;
    if (kp < 216) { j = kp / 9;       w = kp % 9; }
    else          { j = (kp-216) / 3; w = 9 + (kp-216) % 3; }
    v = Wp[(j*12 + w)*64 + n];
  }
  img[t] = f2bf(v);
}

// 15 W1 fragment loads (asm-pinned, 16B-aligned, in-bounds)
#define ISSUE_W1(JN) do { \
  unsigned long long _b = img_u + (unsigned long long)(JN)*15360ull; \
  asm volatile( \
    "global_load_dwordx4 %0, %15, %16\n"  "global_load_dwordx4 %1, %15, %16 offset:1024\n" \
    "global_load_dwordx4 %2, %15, %16 offset:2048\n" "global_load_dwordx4 %3, %15, %16 offset:3072\n" \
    "global_load_dwordx4 %4, %15, %17\n"  "global_load_dwordx4 %5, %15, %17 offset:1024\n" \
    "global_load_dwordx4 %6, %15, %17 offset:2048\n" "global_load_dwordx4 %7, %15, %17 offset:3072\n" \
    "global_load_dwordx4 %8, %15, %18\n"  "global_load_dwordx4 %9, %15, %18 offset:1024\n" \
    "global_load_dwordx4 %10, %15, %18 offset:2048\n" "global_load_dwordx4 %11, %15, %18 offset:3072\n" \
    "global_load_dwordx4 %12, %15, %19\n" "global_load_dwordx4 %13, %15, %19 offset:1024\n" \
    "global_load_dwordx4 %14, %15, %19 offset:2048\n" \
    : "=&v"(fw1[0]),"=&v"(fw1[1]),"=&v"(fw1[2]),"=&v"(fw1[3]),"=&v"(fw1[4]), \
      "=&v"(fw1[5]),"=&v"(fw1[6]),"=&v"(fw1[7]),"=&v"(fw1[8]),"=&v"(fw1[9]), \
      "=&v"(fw1[10]),"=&v"(fw1[11]),"=&v"(fw1[12]),"=&v"(fw1[13]),"=&v"(fw1[14]) \
    : "v"(voff), "s"(_b), "s"(_b+4096ull), "s"(_b+8192ull), "s"(_b+12288ull) \
    : "memory"); \
} while(0)

// 8 bt dword loads (4B-aligned, in-bounds) + 12 W2 x4 loads. Census: 20.
#define ISSUE_BTW2(J) do { \
  unsigned long long _b = img_u + 368640ull + (unsigned long long)(J)*12288ull; \
  asm volatile( \
    "global_load_dword %0, %20, off\n" \
    "global_load_dword %1, %20, off offset:4\n" \
    "global_load_dword %2, %20, off offset:8\n" \
    "global_load_dword %3, %20, off offset:12\n" \
    "global_load_dword %4, %21, %22\n" \
    "global_load_dword %5, %21, %22 offset:4\n" \
    "global_load_dword %6, %21, %22 offset:8\n" \
    "global_load_dword %7, %21, %22 offset:12\n" \
    "global_load_dwordx4 %8, %23, %24\n"  "global_load_dwordx4 %9, %23, %24 offset:1024\n" \
    "global_load_dwordx4 %10, %23, %24 offset:2048\n" "global_load_dwordx4 %11, %23, %24 offset:3072\n" \
    "global_load_dwordx4 %12, %23, %25\n" "global_load_dwordx4 %13, %23, %25 offset:1024\n" \
    "global_load_dwordx4 %14, %23, %25 offset:2048\n" "global_load_dwordx4 %15, %23, %25 offset:3072\n" \
    "global_load_dwordx4 %16, %23, %26\n" "global_load_dwordx4 %17, %23, %26 offset:1024\n" \
    "global_load_dwordx4 %18, %23, %26 offset:2048\n" "global_load_dwordx4 %19, %23, %26 offset:3072\n" \
    : "=&v"(d0),"=&v"(d1),"=&v"(d2),"=&v"(d3),"=&v"(d4),"=&v"(d5),"=&v"(d6),"=&v"(d7), \
      "=&v"(fw2[0]),"=&v"(fw2[1]),"=&v"(fw2[2]),"=&v"(fw2[3]),"=&v"(fw2[4]),"=&v"(fw2[5]), \
      "=&v"(fw2[6]),"=&v"(fw2[7]),"=&v"(fw2[8]),"=&v"(fw2[9]),"=&v"(fw2[10]),"=&v"(fw2[11]) \
    : "v"(aA), "v"(vB), "s"(pose_u), "v"(voff), \
      "s"(_b), "s"(_b+4096ull), "s"(_b+8192ull) \
    : "memory"); \
} while(0)

#define WAITV(N) do { asm volatile("s_waitcnt vmcnt(" #N ")" ::: "memory"); \
                      __builtin_amdgcn_sched_barrier(0); } while(0)

// 256 threads = 4 waves; wave owns 32 rows + whole tree. ZERO barriers.
// Census: I:8 stores | A:20 (bt8+W2x12) | F:15 (W1 next)
//   C waits 28 (retire W1[j]; stores+bt/W2 in flight); H waits 15. Peak 43.
__global__ __launch_bounds__(256, 2) void enc_kernel(
    const float* __restrict__ pose, const float* __restrict__ rel,
    const float* __restrict__ bp,  const short* __restrict__ img,
    float* __restrict__ out) {
  __shared__ __align__(16) short lds[4*10240];       // 81,920 B -> 2 WG/CU

  const int tid  = threadIdx.x;
  const int lane = tid & 63;
  const int wv   = tid >> 6;
  short* myl   = lds + wv*10240;
  short* featL = myl;                                // 3 x [32][72] = 6912
  short* hL    = myl + 6912;                         // [32][80] = 2560
  short* btL   = myl + 9472;                         // [32][24] = 768

  const int cl  = lane & 15;
  const int g   = lane >> 4;
  const int rw0 = blockIdx.x*128 + wv*32;
  const short8 zz = {0,0,0,0,0,0,0,0};
  const unsigned long long img_u  = (unsigned long long)img;
  const unsigned long long pose_u = (unsigned long long)pose;
  const unsigned long long rel_u  = (unsigned long long)rel;
  const unsigned voff = (unsigned)lane << 4;
  const int btr = lane >> 1, btq = lane & 1;
  const unsigned btProw = (unsigned)((rw0 + btr)*864);   // pose row byte base
  const unsigned btRrow = (unsigned)((rw0 + btr)*288);   // rel  row byte base

  short8 fw1[15], fw2[12];
  float d0, d1, d2, d3, d4, d5, d6, d7;

  // ---- prologue: bt[joint 0] + bias vector (compiler loads, pre-asm) ----
  {
    const float* pb = pose + (size_t)(rw0 + btr)*216;
    const float* rb = rel  + (size_t)(rw0 + btr)*72;
    short8 w;
    if (btq == 0) {
      w = pk8(*(const f32x4*)pb, *(const f32x4*)(pb + 4));
    } else {
      float r0 = rb[0], r1 = rb[1], r2 = rb[2];
      float nv = sqrtf(r0*r0 + r1*r1 + r2*r2);
      w[0]=sbf(pb[8]); w[1]=sbf(r0); w[2]=sbf(r1); w[3]=sbf(r2);
      w[4]=sbf(nv); w[5]=(short)0x3F80; w[6]=0; w[7]=0;   // col13 = 1.0
    }
    *(short8*)(btL + btr*24 + btq*8) = w;
  }
  f32x4 bpv[4];
#pragma unroll
  for (int nt = 0; nt < 4; ++nt) bpv[nt] = *(const f32x4*)(bp + nt*16 + g*4);

  // ---- root: WpT (A) x bonefeat (B) -> feat slot 2 ----
  f32x4 racc[2][4] = {};
  {
    const float* pr0 = pose + (size_t)(rw0 + cl)*216;
    const float* rr0 = rel  + (size_t)(rw0 + cl)*72;
    const float* pr1 = pose + (size_t)(rw0 + 16 + cl)*216;
    const float* rr1 = rel  + (size_t)(rw0 + 16 + cl)*72;
    const short8* fpg = (const short8*)(img + FP_OFF) + lane;
    short8 av0[9], av1[9];
#pragma unroll
    for (int s = 0; s < 9; ++s) {
      int k0 = s*32 + g*8;
      const float* s0 = (k0 < 216) ? (pr0 + k0) : (rr0 + (k0 - 216));
      const float* s1 = (k0 < 216) ? (pr1 + k0) : (rr1 + (k0 - 216));
      av0[s] = pk8(*(const f32x4*)s0, *(const f32x4*)(s0 + 4));
      av1[s] = pk8(*(const f32x4*)s1, *(const f32x4*)(s1 + 4));
    }
#pragma unroll
    for (int nt = 0; nt < 4; ++nt) {
      short8 fwp[9];
#pragma unroll
      for (int s = 0; s < 9; ++s) fwp[s] = fpg[(nt*9 + s)*64];
#pragma unroll
      for (int s = 0; s < 9; ++s) {
        racc[0][nt] = MFMA(fwp[s], av0[s], racc[0][nt]);
        racc[1][nt] = MFMA(fwp[s], av1[s], racc[1][nt]);
      }
    }
  }
  // root epilogue: lane holds feat[n=nt*16+g*4+r][batch=m*16+cl]
#pragma unroll
  for (int nt = 0; nt < 4; ++nt) {
#pragma unroll
    for (int m = 0; m < 2; ++m) {
      f32x4 v = racc[m][nt];
      v[0]+=bpv[nt][0]; v[1]+=bpv[nt][1]; v[2]+=bpv[nt][2]; v[3]+=bpv[nt][3];
      *(s4*)(featL + 2*2304 + (m*16 + cl)*72 + nt*16 + g*4) = pk4(v);
    }
  }

  ISSUE_W1(0);                                       // first asm VMEM; census 15

  // ---- main DFS loop ----
#pragma unroll 1
  for (int p = 0; p < NJ; ++p) {
    const int j  = ORD[p];
    const int ps = PSL[p];
    const int ss = SSL[p];
    const int jn = (p < NJ-1) ? ORD[p+1] : 0;        // dummy jn=0 on last iter

    // B-fragments from LDS (lgkm only): x[k][batch]
    const short* fb0 = featL + ps*2304 + cl*72;
    const short* fb1 = featL + ps*2304 + (16 + cl)*72;
    short8 a0[2], a1[2], a2[2];
    a0[0] = (g < 2) ? *(const short8*)(btL + cl*24 + g*8)
                    : *(const short8*)(fb0 + (g-2)*8);
    a0[1] = (g < 2) ? *(const short8*)(btL + (16+cl)*24 + g*8)
                    : *(const short8*)(fb1 + (g-2)*8);
    a1[0] = *(const short8*)(fb0 + 16 + g*8);
    a1[1] = *(const short8*)(fb1 + 16 + g*8);
    a2[0] = (g < 2) ? *(const short8*)(fb0 + 48 + g*8) : zz;
    a2[1] = (g < 2) ? *(const short8*)(fb1 + 48 + g*8) : zz;

    // A: bt(jn) dwords + W2(j) x4s
    const unsigned long long aA =
        btq ? (rel_u  + btRrow + (unsigned)(jn ? jn*12 - 4 : 0))
            : (pose_u + btProw + (unsigned)(jn*36));
    const unsigned vB = btProw + (unsigned)(jn*36) + (btq ? 20u : 16u);
    ISSUE_BTW2(j);

    // C: retire W1[j] only
    if (p == 0) { WAITV(20); } else { WAITV(28); }

    // D: GEMM1 swapped — lane gets h[n=nt*16+g*4+r][batch=cl]
#pragma unroll
    for (int nt = 0; nt < 5; ++nt) {
      f32x4 c0 = {0,0,0,0}, c1 = {0,0,0,0};
      c0 = MFMA(fw1[nt*3+0], a0[0], c0);  c1 = MFMA(fw1[nt*3+0], a0[1], c1);
      c0 = MFMA(fw1[nt*3+1], a1[0], c0);  c1 = MFMA(fw1[nt*3+1], a1[1], c1);
      c0 = MFMA(fw1[nt*3+2], a2[0], c0);  c1 = MFMA(fw1[nt*3+2], a2[1], c1);
      *(s4*)(hL + cl*80 + nt*16 + g*4)        = pk4(relu4(c0));
      *(s4*)(hL + (16 + cl)*80 + nt*16 + g*4) = pk4(relu4(c1));
    }
    // E: h B-fragments (lgkm)
    short8 h0[2], h1[2], h2[2];
#pragma unroll
    for (int m = 0; m < 2; ++m) {
      const short* hb = hL + (m*16 + cl)*80;
      h0[m] = *(const short8*)(hb + g*8);
      h1[m] = *(const short8*)(hb + 32 + g*8);
      h2[m] = (g < 2) ? *(const short8*)(hb + 64 + g*8) : zz;  // incl h[77]=1 -> b2
    }

    ISSUE_W1(jn);                                    // F: census 15
    WAITV(15);                                       // H: retire stores + bt/W2

    // decode bt(jn) -> btL (col13 = 1.0)
    {
      f32x4 lo = {d0, d1, d2, d3}, hi = {d4, d5, d6, d7};
      short8 wA = pk8(lo, hi);                       // btq=0: pose f0..f7
      float r0 = jn ? d1 : d0;                       // btq=1: rel r0..r2
      float r1 = jn ? d2 : d1;
      float r2 = jn ? d3 : d2;
      float nv = sqrtf(r0*r0 + r1*r1 + r2*r2);
      short8 wB;
      wB[0]=sbf(d7);   wB[1]=sbf(r0); wB[2]=sbf(r1); wB[3]=sbf(r2);
      wB[4]=sbf(nv); wB[5]=(short)0x3F80; wB[6]=0; wB[7]=0;
      short8 w = btq ? wB : wA;
      *(short8*)(btL + btr*24 + btq*8) = w;
    }

    // I: GEMM2 swapped — lane gets out[col=j*64+nt*16+g*4+r][batch=m*16+cl]
#pragma unroll
    for (int nt = 0; nt < 4; ++nt) {
      f32x4 c0 = {0,0,0,0}, c1 = {0,0,0,0};
      c0 = MFMA(fw2[nt*3+0], h0[0], c0);  c1 = MFMA(fw2[nt*3+0], h0[1], c1);
      c0 = MFMA(fw2[nt*3+1], h1[0], c0);  c1 = MFMA(fw2[nt*3+1], h1[1], c1);
      c0 = MFMA(fw2[nt*3+2], h2[0], c0);  c1 = MFMA(fw2[nt*3+2], h2[1], c1);
      f32x4 v0 = relu4(c0), v1 = relu4(c1);
      float* o0 = out + (size_t)(rw0 + cl)*1536      + (size_t)j*64 + nt*16 + g*4;
      float* o1 = out + (size_t)(rw0 + 16 + cl)*1536 + (size_t)j*64 + nt*16 + g*4;
      __builtin_nontemporal_store(v0, (f32x4*)o0);
      __builtin_nontemporal_store(v1, (f32x4*)o1);
      if (ss >= 0) {
        *(s4*)(featL + ss*2304 + cl*72 + nt*16 + g*4)        = pk4(v0);
        *(s4*)(featL + ss*2304 + (16 + cl)*72 + nt*16 + g*4) = pk4(v1);
      }
    }
  }
}

extern "C" void kernel_launch(void* const* d_in, const int* in_sizes, int n_in,
                              void* d_out, int out_size, void* d_ws, size_t ws_size,
                              hipStream_t stream) {
  const float* pose = (const float*)d_in[0];
  const float* rel  = (const float*)d_in[1];
  const float* Wp   = (const float*)d_in[2];
  const float* bp   = (const float*)d_in[3];
  const float* W1   = (const float*)d_in[4];
  const float* b1   = (const float*)d_in[5];
  const float* W2   = (const float*)d_in[6];
  const float* b2   = (const float*)d_in[7];
  float* outp = (float*)d_out;
  short* img  = (short*)d_ws;
  const int Bn = in_sizes[0] / 216;
  prep_kernel<<<(IMG_SHORTS + 255)/256, 256, 0, stream>>>(W1, W2, Wp, b1, b2, img);
  enc_kernel<<<Bn/128, 256, 0, stream>>>(pose, rel, bp, img, outp);
}